// Round 1
// baseline (214.410 us; speedup 1.0000x reference)
//
#include <hip/hip_runtime.h>
#include <hip/hip_bf16.h>

// N,C,K,P,Q,PS = 32,128,128,64,64,3
#define NN 32
#define CCH 128
#define KK 128
#define PP 64
#define QQ 64

typedef __bf16 bf16x8 __attribute__((ext_vector_type(8)));
typedef float f32x16 __attribute__((ext_vector_type(16)));
typedef float f32x4 __attribute__((ext_vector_type(4)));

// Workspace:
//   xT: [N][8 cc][P][Q][16 c] bf16 = 33,554,432 B   (c-chunk-major!)
//   Wf: [8 cc][9 t][4 kb][64 lane][8 bf16] = 294,912 B
#define XT_ELEMS (32ull * 64 * 64 * 128)

// ---------- prep 1: x (NCHW f32) -> xT ([n][cc][p][q][16c] bf16) ----------
// (unchanged from previous round — verified)
__global__ __launch_bounds__(256) void prep_x(const float* __restrict__ x,
                                              __bf16* __restrict__ xT) {
    __shared__ float tile[128 * 64];
    const int t = threadIdx.x;
    const int p = blockIdx.x;
    const int n = blockIdx.y;

#pragma unroll
    for (int pass = 0; pass < 8; ++pass) {
        int idx = pass * 256 + t;
        int qf = idx & 15;
        int c  = idx >> 4;
        f32x4 v = *(const f32x4*)(x + (((size_t)n * CCH + c) * PP + p) * QQ + qf * 4);
        int key = ((c >> 3) & 15) * 4;
        *(f32x4*)(tile + c * 64 + ((qf * 4) ^ key)) = v;
    }
    __syncthreads();

#pragma unroll
    for (int pass = 0; pass < 4; ++pass) {
        int cc   = pass * 2 + (t >> 7);
        int rem  = t & 127;
        int q    = rem >> 1;
        int half = rem & 1;
        int c0   = cc * 16 + half * 8;
        int key  = ((c0 >> 3) & 15) * 4;
        bf16x8 o;
#pragma unroll
        for (int j = 0; j < 8; ++j) o[j] = (__bf16)tile[(c0 + j) * 64 + (q ^ key)];
        *(bf16x8*)(xT + ((((size_t)n * 8 + cc) * PP + p) * QQ + q) * 16 + half * 8) = o;
    }
}

// ---------- prep 2: W -> Wf fragment order (unchanged — verified) ----------
__global__ __launch_bounds__(256) void prep_w(const float* __restrict__ W,
                                              __bf16* __restrict__ Wf) {
    const int id = blockIdx.x * 256 + threadIdx.x;  // 18432
    const int lane = id & 63;
    const int r1   = id >> 6;
    const int kb   = r1 & 3;
    const int r2   = r1 >> 2;
    const int t    = r2 % 9;
    const int cc   = r2 / 9;

    const int k  = kb * 32 + (lane & 31);
    const int c0 = cc * 16 + (lane >> 5) * 8;

    bf16x8 o;
#pragma unroll
    for (int j = 0; j < 8; ++j)
        o[j] = (__bf16)W[(size_t)k * (CCH * 9) + (size_t)(c0 + j) * 9 + t];
    ((bf16x8*)Wf)[id] = o;
}

// ---------- main: implicit GEMM conv, single-barrier double-buffered ----------
// Block: 8 p-rows x 64 q x 128 k, 512 threads (8 waves). Wave: kbs = w&1,
// pb = w>>1 (2 output rows each). Grid 8x32 = 256 blocks = 1 block/CU.
// Per cc (16 c): BOTH operands double-buffered in LDS:
//   wlds[2][36864]  (W chunk),  xlds[2][10*XPITCH]  (rows p0-1 .. p0+8).
// Pipeline: issue stage(cc+1 -> buf^1) BEFORE compute(cc); ONE __syncthreads
// per cc. The barrier's implicit vmcnt(0) drain then waits on loads that had
// a full compute phase in flight (vs the old 2-barrier structure that exposed
// full staging latency+transfer every phase -> MfmaUtil 22%).
// LDS total = 2*36864 + 2*21120 = 115,968 B (<=160 KB, 1 block/CU; occupancy
// is reg-capped at 8 waves/CU either way: 128 VGPR + 128 AGPR = 256/wave).
#define XPITCH 2112  // bytes per padded x row in LDS (66 * 32)
#define WBYTES 36864
#define XROWS  10
#define XBYTES (XROWS * XPITCH)  // 21,120

__global__ __launch_bounds__(512, 2) void conv_main(const __bf16* __restrict__ xT,
                                                    const __bf16* __restrict__ Wf,
                                                    const float* __restrict__ per,
                                                    float* __restrict__ out) {
    __shared__ __align__(16) char wlds[2][WBYTES];
    __shared__ __align__(16) char xlds[2][XBYTES];

    const int tid  = threadIdx.x;
    const int lane = tid & 63;
    const int w    = tid >> 6;   // 0..7
    const int kbs  = w & 1;
    const int pb   = w >> 1;     // 0..3
    const int n    = blockIdx.y;
    const int p0   = blockIdx.x * 8;
    const int m    = lane & 31;
    const int half = lane >> 5;

    // zero the pad columns (q=-1 and q=64 slots) in BOTH buffers, once;
    // staging never touches them (writes only [32, 2080) per row)
    if (tid < 40) {
        int row = tid >> 2, part = tid & 3;
        int off = row * XPITCH + (part >> 1) * 2080 + (part & 1) * 16;
        *(f32x4*)(xlds[0] + off) = f32x4{0.f, 0.f, 0.f, 0.f};
        *(f32x4*)(xlds[1] + off) = f32x4{0.f, 0.f, 0.f, 0.f};
    }

    f32x16 acc[2][2][2];  // [oi][kb][qb]
#pragma unroll
    for (int a = 0; a < 2; ++a)
#pragma unroll
        for (int b = 0; b < 2; ++b)
#pragma unroll
            for (int c = 0; c < 2; ++c)
#pragma unroll
                for (int e = 0; e < 16; ++e) acc[a][b][c][e] = 0.f;

    const char* xb = (const char*)xT + ((size_t)n * 8) * PP * QQ * 32;  // + cc*PP*QQ*32

    // stage cc-chunk ccn into buffer buf: W 36,864 B (2304 x 16 B) +
    // x 10 rows (1280 x 16 B). Guards are full-wave granular (multiples of 64).
    auto stage = [&](int ccn, int buf) {
        const char* g = (const char*)Wf + (size_t)ccn * WBYTES;
#pragma unroll
        for (int it = 0; it < 5; ++it) {
            int idx = it * 512 + tid;
            if (idx < WBYTES / 16) {
                __builtin_amdgcn_global_load_lds(
                    (const __attribute__((address_space(1))) unsigned int*)(g + idx * 16),
                    (__attribute__((address_space(3))) unsigned int*)(wlds[buf] + idx * 16),
                    16, 0, 0);
            }
        }
        const char* gx = xb + (size_t)ccn * (PP * QQ * 32);
#pragma unroll
        for (int it = 0; it < 3; ++it) {
            int gi = it * 512 + tid;
            if (gi < XROWS * 128) {
                int row = gi >> 7;              // wave-uniform (64 | 128)
                int wi  = (gi & 127) * 16;
                int r   = p0 - 1 + row;
                int rc  = r < 0 ? 0 : (r > 63 ? 63 : r);
                __builtin_amdgcn_global_load_lds(
                    (const __attribute__((address_space(1))) unsigned int*)(gx + (size_t)rc * 2048 + wi),
                    (__attribute__((address_space(3))) unsigned int*)(xlds[buf] + row * XPITCH + 32 + wi),
                    16, 0, 0);
            }
        }
    };

    stage(0, 0);
    __syncthreads();  // prologue: only exposed staging wait in the kernel

    int cur = 0;
    for (int cc = 0; cc < 8; ++cc) {
        if (cc < 7) stage(cc + 1, cur ^ 1);   // issue BEFORE compute -> overlap

        const char* wbase = wlds[cur];
        const char* xbase = xlds[cur];

        bf16x8 a_cur[3][2], a_prev[3][2];
#pragma unroll
        for (int ri = 0; ri < 4; ++ri) {
            const int rr = pb * 2 + ri;            // xlds row 0..9
            const int r  = p0 + pb * 2 + ri - 1;   // global input row
            const bool rok = ((unsigned)r < (unsigned)PP);  // wave-uniform

            // B frags for input row rr: q_in+1 = qb*32 + m + dq (pad handles edges)
            bf16x8 b[3][2];
            if (rok) {
                const char* rbase = xbase + rr * XPITCH + half * 16;
#pragma unroll
                for (int dq = 0; dq < 3; ++dq)
#pragma unroll
                    for (int qb = 0; qb < 2; ++qb)
                        b[dq][qb] = *(const bf16x8*)(rbase + (qb * 32 + m + dq) * 32);
            }

            // A frags for tap row ri (consumed by oi=0 now, oi=1 at ri+1)
            if (ri < 3) {
#pragma unroll
                for (int dq = 0; dq < 3; ++dq)
#pragma unroll
                    for (int kb = 0; kb < 2; ++kb)
                        a_cur[dq][kb] = ((const bf16x8*)wbase)[((ri * 3 + dq) * 4 +
                                                                kbs * 2 + kb) * 64 + lane];
            }

            if (rok) {
                if (ri >= 1) {
#pragma unroll
                    for (int dq = 0; dq < 3; ++dq)
#pragma unroll
                        for (int kb = 0; kb < 2; ++kb)
#pragma unroll
                            for (int qb = 0; qb < 2; ++qb)
                                acc[1][kb][qb] = __builtin_amdgcn_mfma_f32_32x32x16_bf16(
                                    a_prev[dq][kb], b[dq][qb], acc[1][kb][qb], 0, 0, 0);
                }
                if (ri < 3) {
#pragma unroll
                    for (int dq = 0; dq < 3; ++dq)
#pragma unroll
                        for (int kb = 0; kb < 2; ++kb)
#pragma unroll
                            for (int qb = 0; qb < 2; ++qb)
                                acc[0][kb][qb] = __builtin_amdgcn_mfma_f32_32x32x16_bf16(
                                    a_cur[dq][kb], b[dq][qb], acc[0][kb][qb], 0, 0, 0);
                }
            }

            if (ri < 3) {
#pragma unroll
                for (int dq = 0; dq < 3; ++dq)
#pragma unroll
                    for (int kb = 0; kb < 2; ++kb) a_prev[dq][kb] = a_cur[dq][kb];
            }
        }

        __syncthreads();  // all waves done reading buf[cur]; drains stage(cc+1)
        cur ^= 1;
    }

    // Epilogue: D col = q (coalesced), row = k; fused perturb add.
#pragma unroll
    for (int oi = 0; oi < 2; ++oi) {
        const int prow = p0 + pb * 2 + oi;
#pragma unroll
        for (int kbi = 0; kbi < 2; ++kbi) {
#pragma unroll
            for (int qb = 0; qb < 2; ++qb) {
                f32x16 v = acc[oi][kbi][qb];
#pragma unroll
                for (int r = 0; r < 16; ++r) {
                    int krow = (r & 3) + 8 * (r >> 2) + 4 * half;
                    int k    = (kbs * 2 + kbi) * 32 + krow;
                    int q    = qb * 32 + m;
                    size_t oidx = (((size_t)n * KK + k) * PP + prow) * QQ + q;
                    out[oidx] = v[r] + per[oidx];
                }
            }
        }
    }
}

extern "C" void kernel_launch(void* const* d_in, const int* in_sizes, int n_in,
                              void* d_out, int out_size, void* d_ws, size_t ws_size,
                              hipStream_t stream) {
    const float* x   = (const float*)d_in[0];  // [32][128][64][64]
    const float* W   = (const float*)d_in[1];  // [128][1152]
    const float* per = (const float*)d_in[2];  // [32][128][64][64]
    float* out = (float*)d_out;

    __bf16* xT = (__bf16*)d_ws;
    __bf16* Wf = (__bf16*)((char*)d_ws + XT_ELEMS * 2);

    prep_x<<<dim3(PP, NN), 256, 0, stream>>>(x, xT);
    prep_w<<<dim3(72), 256, 0, stream>>>(W, Wf);
    conv_main<<<dim3(PP / 8, NN), 512, 0, stream>>>(xT, Wf, per, out);
}